// Round 5
// baseline (924.793 us; speedup 1.0000x reference)
//
#include <hip/hip_runtime.h>

// ---------- types ----------
typedef __attribute__((ext_vector_type(8))) short bf16x8;
typedef __attribute__((ext_vector_type(4))) float f32x4;

static __device__ __forceinline__ unsigned short f2bf(float x) {
    unsigned int u = __float_as_uint(x);
    u += 0x7fffu + ((u >> 16) & 1u);   // RTNE, finite inputs
    return (unsigned short)(u >> 16);
}

// Workgroup barrier WITHOUT vmcnt drain: LDS ordering only.
// Safe when no global-memory producer/consumer relationship crosses the barrier.
static __device__ __forceinline__ void barrier_lds_only() {
    __asm__ volatile("s_waitcnt lgkmcnt(0)\n\ts_barrier" ::: "memory");
}

// ---------- K0: four fp32->bf16 transposes in one launch ----------
__global__ void transpose4(const float* __restrict__ s0, const float* __restrict__ s1,
                           const float* __restrict__ s2, const float* __restrict__ s3,
                           unsigned short* __restrict__ d0, unsigned short* __restrict__ d1,
                           unsigned short* __restrict__ d2, unsigned short* __restrict__ d3) {
    int which = blockIdx.y;
    const float* src = which == 0 ? s0 : which == 1 ? s1 : which == 2 ? s2 : s3;
    unsigned short* dst = which == 0 ? d0 : which == 1 ? d1 : which == 2 ? d2 : d3;
    int K = (which == 0) ? 512 : 256;
    int idx = blockIdx.x * 256 + threadIdx.x;
    if (idx >= K * 256) return;
    int k = idx >> 8;          // N = 256
    int n = idx & 255;
    dst[n * K + k] = f2bf(src[idx]);
}

// ---------- GEMM: C[M,N] = A[M,K] @ Bt[N,K]^T + bias, bf16 MFMA ----------
template<bool GATHER>
__global__ __launch_bounds__(256, 4) void gemm_mfma(
    const void* __restrict__ Aptr, const int* __restrict__ tokens,
    const unsigned short* __restrict__ Bt, const float* __restrict__ bias,
    float* __restrict__ C, int M, int N, int K)
{
    const int bn0 = blockIdx.x * 64;
    const int m0  = blockIdx.y * 64;
    const int tid = threadIdx.x;

    __shared__ unsigned short As[64 * 40];
    __shared__ unsigned short Bs[64 * 40];
    __shared__ int tok[64];

    if (GATHER) {
        if (tid < 64) tok[tid] = tokens[m0 + tid];
        __syncthreads();
    }

    const int r  = tid >> 2;
    const int c0 = (tid & 3) * 8;
    const int w  = tid >> 6;
    const int L  = tid & 63;
    const int ml = L & 15;
    const int q  = L >> 4;
    const int kq = q * 8;

    f32x4 acc[4] = {};

    for (int k0 = 0; k0 < K; k0 += 32) {
        unsigned short tmp[8];
        if (GATHER) {
            const float* src = (const float*)Aptr + (size_t)tok[r] * K + k0 + c0;
            float4 f0 = *(const float4*)(src);
            float4 f1 = *(const float4*)(src + 4);
            tmp[0]=f2bf(f0.x); tmp[1]=f2bf(f0.y); tmp[2]=f2bf(f0.z); tmp[3]=f2bf(f0.w);
            tmp[4]=f2bf(f1.x); tmp[5]=f2bf(f1.y); tmp[6]=f2bf(f1.z); tmp[7]=f2bf(f1.w);
        } else {
            const unsigned short* src = (const unsigned short*)Aptr + (size_t)(m0 + r) * K + k0 + c0;
            *(uint4*)tmp = *(const uint4*)src;
        }
        *(uint4*)&As[r * 40 + c0] = *(const uint4*)tmp;
        *(uint4*)&Bs[r * 40 + c0] = *(const uint4*)(Bt + (size_t)(bn0 + r) * K + k0 + c0);
        __syncthreads();

        bf16x8 av = *(const bf16x8*)&As[(16 * w + ml) * 40 + kq];
#pragma unroll
        for (int ns = 0; ns < 4; ++ns) {
            bf16x8 bv = *(const bf16x8*)&Bs[(ns * 16 + ml) * 40 + kq];
            acc[ns] = __builtin_amdgcn_mfma_f32_16x16x32_bf16(av, bv, acc[ns], 0, 0, 0);
        }
        __syncthreads();
    }

#pragma unroll
    for (int ns = 0; ns < 4; ++ns) {
        int gn = bn0 + ns * 16 + ml;
        float bv = bias[gn];
#pragma unroll
        for (int rr = 0; rr < 4; ++rr) {
            int gm = m0 + 16 * w + q * 4 + rr;
            C[(size_t)gm * N + gn] = acc[ns][rr] + bv;
        }
    }
}

// ---------- MFMA scan, K-SPLIT: h_t = tanh(xw_t + h_{t-1} @ U) ----------
// One WG (256 thr = 4 waves) per batch row. Wave w owns k-slice [w*64, w*64+64):
// reads only 2 b128 of h per step (8/CU, was 32/CU), computes PARTIAL z for all
// 256 cols (16 n-tiles x 2 kt = 32 MFMA), writes partials to LDS. After barrier,
// lane tid reduces the 4 wave-partials for col=tid, adds xw, tanh, writes h.
// Two lds-only barriers per step; zero-init via loop-invariant zero C operand.
template<bool SEQ>
__global__ __launch_bounds__(256, 1) void rnn_scan_mfma(
    const float* __restrict__ xw,           // [64][512][256] f32
    const unsigned short* __restrict__ Ut,  // [256][256] bf16, Ut[n][k] = U[k][n]
    unsigned short* __restrict__ out_seq,   // bf16 [64][512][256]  (SEQ)
    float* __restrict__ out_last)           // f32 [64][256]        (!SEQ)
{
    const int b   = blockIdx.x;
    const int tid = threadIdx.x;
    const int w   = tid >> 6;       // wave 0..3 -> k-slice
    const int L   = tid & 63;
    const int q   = L >> 4;         // quad
    const int ml  = L & 15;

    __shared__ unsigned short hsh[256];     // h state, bf16
    __shared__ float part[4][256];          // per-wave partial z

    // B-frags: ufrag[i][j] covers n-tile i (cols i*16..i*16+15), k = w*64 + j*32 + q*8
    bf16x8 ufrag[16][2];
#pragma unroll
    for (int i = 0; i < 16; ++i) {
        const unsigned short* up = Ut + (size_t)(i * 16 + ml) * 256 + w * 64 + q * 8;
        ufrag[i][0] = *(const bf16x8*)(up);
        ufrag[i][1] = *(const bf16x8*)(up + 32);
    }

    hsh[tid] = 0;   // bf16 +0.0

    // A-frag LDS addresses (this wave's k-slice; broadcast within quad)
    const unsigned short* ha0 = &hsh[w * 64 + q * 8];
    const unsigned short* ha1 = &hsh[w * 64 + 32 + q * 8];

    // partial-write addresses: tuple i = 4*jj + q -> col = (4*jj+q)*16 + ml
    float* pw0 = &part[w][(4 * 0 + q) * 16 + ml];
    float* pw1 = &part[w][(4 * 1 + q) * 16 + ml];
    float* pw2 = &part[w][(4 * 2 + q) * 16 + ml];
    float* pw3 = &part[w][(4 * 3 + q) * 16 + ml];

    const float* xb = xw + (size_t)b * 512 * 256 + tid;
    unsigned short* op = SEQ ? out_seq + (size_t)b * 512 * 256 + tid : nullptr;

    // 4-deep xw prefetch pipeline
    float xq0 = xb[0 * 256];
    float xq1 = xb[1 * 256];
    float xq2 = xb[2 * 256];
    float xq3 = xb[3 * 256];
    const float* xpf = xb + 4 * 256;

    const f32x4 zf = {0.f, 0.f, 0.f, 0.f};  // loop-invariant zero C operand
    float lastv = 0.f;
    __syncthreads();

#define SCAN_STEP(XQ, PF)                                                            \
    {                                                                                \
        bf16x8 af0 = *(const bf16x8*)ha0;                                            \
        bf16x8 af1 = *(const bf16x8*)ha1;                                            \
        float xnew = 0.f;                                                            \
        if (PF) { xnew = *xpf; xpf += 256; }                                         \
        f32x4 acc[16];                                                               \
        _Pragma("unroll")                                                            \
        for (int i = 0; i < 16; ++i)                                                 \
            acc[i] = __builtin_amdgcn_mfma_f32_16x16x32_bf16(af0, ufrag[i][0], zf, 0, 0, 0); \
        _Pragma("unroll")                                                            \
        for (int i = 0; i < 16; ++i)                                                 \
            acc[i] = __builtin_amdgcn_mfma_f32_16x16x32_bf16(af1, ufrag[i][1], acc[i], 0, 0, 0); \
        float v0 = (q == 0) ? acc[0][0]  : (q == 1) ? acc[1][0]  : (q == 2) ? acc[2][0]  : acc[3][0];  \
        float v1 = (q == 0) ? acc[4][0]  : (q == 1) ? acc[5][0]  : (q == 2) ? acc[6][0]  : acc[7][0];  \
        float v2 = (q == 0) ? acc[8][0]  : (q == 1) ? acc[9][0]  : (q == 2) ? acc[10][0] : acc[11][0]; \
        float v3 = (q == 0) ? acc[12][0] : (q == 1) ? acc[13][0] : (q == 2) ? acc[14][0] : acc[15][0]; \
        *pw0 = v0; *pw1 = v1; *pw2 = v2; *pw3 = v3;                                  \
        barrier_lds_only();                       /* partials visible */             \
        float p0 = part[0][tid], p1 = part[1][tid], p2 = part[2][tid], p3 = part[3][tid]; \
        float z = ((p0 + p1) + (p2 + p3)) + XQ;                                      \
        float e  = __expf(2.f * z);               /* tanh(z) = 1 - 2/(e^{2z}+1) */   \
        float hn = 1.f - 2.f * __builtin_amdgcn_rcpf(e + 1.f);                       \
        lastv = hn;                                                                  \
        unsigned short hb = f2bf(hn);                                                \
        hsh[tid] = hb;                                                               \
        if (SEQ) { *op = hb; op += 256; }                                            \
        XQ = xnew;                                                                   \
        barrier_lds_only();                       /* h_new + part reads retired */   \
    }

    // 127 chunks x 4 steps: t = 0..507, prefetch in-bounds (last loads t=511)
    for (int tt = 0; tt < 508; tt += 4) {
        SCAN_STEP(xq0, 1)
        SCAN_STEP(xq1, 1)
        SCAN_STEP(xq2, 1)
        SCAN_STEP(xq3, 1)
    }
    // epilogue: t = 508..511, no prefetch
    SCAN_STEP(xq0, 0)
    SCAN_STEP(xq1, 0)
    SCAN_STEP(xq2, 0)
    SCAN_STEP(xq3, 0)
#undef SCAN_STEP

    if (!SEQ) out_last[b * 256 + tid] = lastv;
}

// ---------- head: softmax(h2 @ Wd + bd) ----------
__global__ void head_kernel(const float* __restrict__ h2, const float* __restrict__ Wd,
                            const float* __restrict__ bd, float* __restrict__ out)
{
    int tid = threadIdx.x;         // 128 threads: b = tid>>1, c = tid&1
    int b = tid >> 1, c = tid & 1;
    float s = bd[c];
    for (int jj = 0; jj < 256; ++jj) s = fmaf(h2[b * 256 + jj], Wd[jj * 2 + c], s);
    __shared__ float lg[128];
    lg[tid] = s;
    __syncthreads();
    float o0 = lg[b * 2 + 0], o1 = lg[b * 2 + 1];
    float m = fmaxf(o0, o1);
    float z = __expf(o0 - m) + __expf(o1 - m);
    out[tid] = __expf(s - m) * __builtin_amdgcn_rcpf(z);
}

// ---------- launch ----------
extern "C" void kernel_launch(void* const* d_in, const int* in_sizes, int n_in,
                              void* d_out, int out_size, void* d_ws, size_t ws_size,
                              hipStream_t stream) {
    const int*   tokens = (const int*)d_in[0];
    const float* emb    = (const float*)d_in[1];
    const float* W1     = (const float*)d_in[2];
    const float* U1     = (const float*)d_in[3];
    const float* b1     = (const float*)d_in[4];
    const float* W2     = (const float*)d_in[5];
    const float* U2     = (const float*)d_in[6];
    const float* b2     = (const float*)d_in[7];
    const float* Wd     = (const float*)d_in[8];
    const float* bd     = (const float*)d_in[9];
    float* out = (float*)d_out;

    char* ws = (char*)d_ws;
    float*          xw  = (float*)ws;                                  // 32 MB (xw1 then xw2)
    unsigned short* h1  = (unsigned short*)(ws + (33554432));          // 16 MB bf16
    char*           p   = ws + 33554432 + 16777216;
    unsigned short* W1t = (unsigned short*)p;            p += 512 * 256 * 2;
    unsigned short* W2t = (unsigned short*)p;            p += 256 * 256 * 2;
    unsigned short* U1t = (unsigned short*)p;            p += 256 * 256 * 2;
    unsigned short* U2t = (unsigned short*)p;            p += 256 * 256 * 2;
    float*          h2  = (float*)p;

    const int M = 64 * 512;   // 32768

    // K0: weight/recurrence transposes to bf16 [N][K]
    transpose4<<<dim3(512, 4), 256, 0, stream>>>(W1, W2, U1, U2, W1t, W2t, U1t, U2t);

    // K1: xw1 = emb[tokens] @ W1 + b1   (gather fused)
    gemm_mfma<true><<<dim3(256 / 64, M / 64), 256, 0, stream>>>(
        emb, tokens, W1t, b1, xw, M, 256, 512);

    // K2: layer-1 scan -> h1 (bf16 sequence)
    rnn_scan_mfma<true><<<64, 256, 0, stream>>>(xw, U1t, h1, nullptr);

    // K3: xw2 = h1 @ W2 + b2
    gemm_mfma<false><<<dim3(256 / 64, M / 64), 256, 0, stream>>>(
        h1, nullptr, W2t, b2, xw, M, 256, 256);

    // K4: layer-2 scan -> h2 (last state, f32)
    rnn_scan_mfma<false><<<64, 256, 0, stream>>>(xw, U2t, nullptr, h2);

    // K5: softmax(h2 @ Wd + bd)
    head_kernel<<<1, 128, 0, stream>>>(h2, Wd, bd, out);
}

// Round 6
// 738.405 us; speedup vs baseline: 1.2524x; 1.2524x over previous
//
#include <hip/hip_runtime.h>

// ---------- types ----------
typedef __attribute__((ext_vector_type(8))) short bf16x8;
typedef __attribute__((ext_vector_type(4))) float f32x4;

static __device__ __forceinline__ unsigned short f2bf(float x) {
    unsigned int u = __float_as_uint(x);
    u += 0x7fffu + ((u >> 16) & 1u);   // RTNE, finite inputs
    return (unsigned short)(u >> 16);
}

// Workgroup barrier WITHOUT vmcnt drain: LDS ordering only.
// Safe when no global-memory producer/consumer relationship crosses the barrier.
static __device__ __forceinline__ void barrier_lds_only() {
    __asm__ volatile("s_waitcnt lgkmcnt(0)\n\ts_barrier" ::: "memory");
}

// ---------- K0: four fp32->bf16 transposes in one launch ----------
__global__ void transpose4(const float* __restrict__ s0, const float* __restrict__ s1,
                           const float* __restrict__ s2, const float* __restrict__ s3,
                           unsigned short* __restrict__ d0, unsigned short* __restrict__ d1,
                           unsigned short* __restrict__ d2, unsigned short* __restrict__ d3) {
    int which = blockIdx.y;
    const float* src = which == 0 ? s0 : which == 1 ? s1 : which == 2 ? s2 : s3;
    unsigned short* dst = which == 0 ? d0 : which == 1 ? d1 : which == 2 ? d2 : d3;
    int K = (which == 0) ? 512 : 256;
    int idx = blockIdx.x * 256 + threadIdx.x;
    if (idx >= K * 256) return;
    int k = idx >> 8;          // N = 256
    int n = idx & 255;
    dst[n * K + k] = f2bf(src[idx]);
}

// ---------- GEMM: C[M,N] = A[M,K] @ Bt[N,K]^T + bias, bf16 MFMA ----------
template<bool GATHER>
__global__ __launch_bounds__(256, 4) void gemm_mfma(
    const void* __restrict__ Aptr, const int* __restrict__ tokens,
    const unsigned short* __restrict__ Bt, const float* __restrict__ bias,
    float* __restrict__ C, int M, int N, int K)
{
    const int bn0 = blockIdx.x * 64;
    const int m0  = blockIdx.y * 64;
    const int tid = threadIdx.x;

    __shared__ unsigned short As[64 * 40];
    __shared__ unsigned short Bs[64 * 40];
    __shared__ int tok[64];

    if (GATHER) {
        if (tid < 64) tok[tid] = tokens[m0 + tid];
        __syncthreads();
    }

    const int r  = tid >> 2;
    const int c0 = (tid & 3) * 8;
    const int w  = tid >> 6;
    const int L  = tid & 63;
    const int ml = L & 15;
    const int q  = L >> 4;
    const int kq = q * 8;

    f32x4 acc[4] = {};

    for (int k0 = 0; k0 < K; k0 += 32) {
        unsigned short tmp[8];
        if (GATHER) {
            const float* src = (const float*)Aptr + (size_t)tok[r] * K + k0 + c0;
            float4 f0 = *(const float4*)(src);
            float4 f1 = *(const float4*)(src + 4);
            tmp[0]=f2bf(f0.x); tmp[1]=f2bf(f0.y); tmp[2]=f2bf(f0.z); tmp[3]=f2bf(f0.w);
            tmp[4]=f2bf(f1.x); tmp[5]=f2bf(f1.y); tmp[6]=f2bf(f1.z); tmp[7]=f2bf(f1.w);
        } else {
            const unsigned short* src = (const unsigned short*)Aptr + (size_t)(m0 + r) * K + k0 + c0;
            *(uint4*)tmp = *(const uint4*)src;
        }
        *(uint4*)&As[r * 40 + c0] = *(const uint4*)tmp;
        *(uint4*)&Bs[r * 40 + c0] = *(const uint4*)(Bt + (size_t)(bn0 + r) * K + k0 + c0);
        __syncthreads();

        bf16x8 av = *(const bf16x8*)&As[(16 * w + ml) * 40 + kq];
#pragma unroll
        for (int ns = 0; ns < 4; ++ns) {
            bf16x8 bv = *(const bf16x8*)&Bs[(ns * 16 + ml) * 40 + kq];
            acc[ns] = __builtin_amdgcn_mfma_f32_16x16x32_bf16(av, bv, acc[ns], 0, 0, 0);
        }
        __syncthreads();
    }

#pragma unroll
    for (int ns = 0; ns < 4; ++ns) {
        int gn = bn0 + ns * 16 + ml;
        float bv = bias[gn];
#pragma unroll
        for (int rr = 0; rr < 4; ++rr) {
            int gm = m0 + 16 * w + q * 4 + rr;
            C[(size_t)gm * N + gn] = acc[ns][rr] + bv;
        }
    }
}

// ---------- MFMA scan, 4-ROW-BATCHED: h_t = tanh(xw_t + h_{t-1} @ U) ----------
// One WG (256 thr = 4 waves) per FOUR batch rows. MFMA A operand packs 4 rows
// (A row m -> batch row m>>2, 4 replicas each): lane (q,ml) reads
// h[row=ml>>2][k=kt*32+q*8..+7] as one ds_read_b128. C layout gives lane (q,ml)
// in chain nt the value z[row=q][col=wl*64+nt*16+ml] in ALL 4 regs -> no selects.
// Same 32 MFMA + 8 LDS reads per wave as the 1-row version, 4x the rows.
// LDS row stride 272 shorts: all access patterns <=2-way bank aliasing (free).
// Double-buffered h, single lds-only barrier per step, 4-deep xw prefetch.
template<bool SEQ>
__global__ __launch_bounds__(256, 1) void rnn_scan_mfma(
    const float* __restrict__ xw,           // [64][512][256] f32
    const unsigned short* __restrict__ Ut,  // [256][256] bf16, Ut[n][k] = U[k][n]
    unsigned short* __restrict__ out_seq,   // bf16 [64][512][256]  (SEQ)
    float* __restrict__ out_last)           // f32 [64][256]        (!SEQ)
{
    const int b0  = blockIdx.x * 4;
    const int tid = threadIdx.x;
    const int wl  = tid >> 6;       // wave 0..3 -> col slice [wl*64, wl*64+64)
    const int L   = tid & 63;
    const int q   = L >> 4;         // quad -> this thread's batch row (b0+q)
    const int ml  = L & 15;

    __shared__ unsigned short hsh[2][4][272];   // [buf][row][col+pad]

    // B-frags: U columns for this wave's 4 n-tiles, all 8 k-tiles (identical to R4)
    bf16x8 ufrag[4][8];
#pragma unroll
    for (int i = 0; i < 4; ++i) {
        const unsigned short* up = Ut + (size_t)((wl * 4 + i) * 16 + ml) * 256 + q * 8;
#pragma unroll
        for (int kt = 0; kt < 8; ++kt)
            ufrag[i][kt] = *(const bf16x8*)(up + kt * 32);
    }

    // zero h buffer 0 (incl. pads, harmless)
    for (int i = tid; i < 4 * 272; i += 256) ((unsigned short*)hsh[0])[i] = 0;

    // A-frag read bases (per buffer): lane reads its batch-row (ml>>2), quad k-slice
    const unsigned short* ha[2] = { &hsh[0][ml >> 2][q * 8], &hsh[1][ml >> 2][q * 8] };
    // h write bases (per buffer): thread writes row q, col wl*64 + nt*16 + ml
    unsigned short* hw[2] = { &hsh[0][q][wl * 64 + ml], &hsh[1][q][wl * 64 + ml] };

    const float* xp = xw + (size_t)(b0 + q) * 512 * 256 + wl * 64 + ml;   // +nt*16 imm
    unsigned short* op = SEQ ? out_seq + (size_t)(b0 + q) * 512 * 256 + wl * 64 + ml : nullptr;

    // 4-deep prefetch pipeline, 4 streams (one per n-tile)
    float xq0[4], xq1[4], xq2[4], xq3[4];
#pragma unroll
    for (int nt = 0; nt < 4; ++nt) {
        xq0[nt] = xp[0 * 256 + nt * 16];
        xq1[nt] = xp[1 * 256 + nt * 16];
        xq2[nt] = xp[2 * 256 + nt * 16];
        xq3[nt] = xp[3 * 256 + nt * 16];
    }
    const float* xpf = xp + 4 * 256;

    const f32x4 zf = {0.f, 0.f, 0.f, 0.f};  // loop-invariant zero C operand
    float lastv[4] = {0.f, 0.f, 0.f, 0.f};
    __syncthreads();

#define SCAN_STEP(CUR, XQ, PF)                                                       \
    {                                                                                \
        bf16x8 af[8];                                                                \
        _Pragma("unroll")                                                            \
        for (int kt = 0; kt < 8; ++kt)                                               \
            af[kt] = *(const bf16x8*)(ha[CUR] + kt * 32);                            \
        float xn[4] = {0.f, 0.f, 0.f, 0.f};                                          \
        if (PF) {                                                                    \
            _Pragma("unroll")                                                        \
            for (int nt = 0; nt < 4; ++nt) xn[nt] = xpf[nt * 16];                    \
            xpf += 256;                                                              \
        }                                                                            \
        f32x4 accA[4], accB[4];                                                      \
        _Pragma("unroll")                                                            \
        for (int i = 0; i < 4; ++i)                                                  \
            accA[i] = __builtin_amdgcn_mfma_f32_16x16x32_bf16(af[0], ufrag[i][0], zf, 0, 0, 0); \
        _Pragma("unroll")                                                            \
        for (int i = 0; i < 4; ++i)                                                  \
            accB[i] = __builtin_amdgcn_mfma_f32_16x16x32_bf16(af[1], ufrag[i][1], zf, 0, 0, 0); \
        _Pragma("unroll")                                                            \
        for (int kt = 2; kt < 8; kt += 2) {                                          \
            _Pragma("unroll")                                                        \
            for (int i = 0; i < 4; ++i)                                              \
                accA[i] = __builtin_amdgcn_mfma_f32_16x16x32_bf16(af[kt], ufrag[i][kt], accA[i], 0, 0, 0);       \
            _Pragma("unroll")                                                        \
            for (int i = 0; i < 4; ++i)                                              \
                accB[i] = __builtin_amdgcn_mfma_f32_16x16x32_bf16(af[kt + 1], ufrag[i][kt + 1], accB[i], 0, 0, 0); \
        }                                                                            \
        unsigned short hb[4];                                                        \
        _Pragma("unroll")                                                            \
        for (int nt = 0; nt < 4; ++nt) {                                             \
            float z = accA[nt][0] + accB[nt][0] + XQ[nt];                            \
            float e = __expf(2.f * z);            /* tanh(z) = 1 - 2/(e^{2z}+1) */   \
            float hn = 1.f - 2.f * __builtin_amdgcn_rcpf(e + 1.f);                   \
            lastv[nt] = hn;                                                          \
            hb[nt] = f2bf(hn);                                                       \
        }                                                                            \
        _Pragma("unroll")                                                            \
        for (int nt = 0; nt < 4; ++nt) hw[(CUR) ^ 1][nt * 16] = hb[nt];              \
        if (SEQ) {                                                                   \
            _Pragma("unroll")                                                        \
            for (int nt = 0; nt < 4; ++nt) op[nt * 16] = hb[nt];                     \
            op += 256;                                                               \
        }                                                                            \
        if (PF) {                                                                    \
            _Pragma("unroll")                                                        \
            for (int nt = 0; nt < 4; ++nt) XQ[nt] = xn[nt];                          \
        }                                                                            \
        barrier_lds_only();                       /* h_new visible; no vmcnt drain */\
    }

    // 127 chunks x 4 steps: t = 0..507, prefetch in-bounds (last loads t=511)
    for (int tt = 0; tt < 508; tt += 4) {
        SCAN_STEP(0, xq0, 1)
        SCAN_STEP(1, xq1, 1)
        SCAN_STEP(0, xq2, 1)
        SCAN_STEP(1, xq3, 1)
    }
    // epilogue: t = 508..511, no prefetch
    SCAN_STEP(0, xq0, 0)
    SCAN_STEP(1, xq1, 0)
    SCAN_STEP(0, xq2, 0)
    SCAN_STEP(1, xq3, 0)
#undef SCAN_STEP

    if (!SEQ) {
#pragma unroll
        for (int nt = 0; nt < 4; ++nt)
            out_last[(b0 + q) * 256 + wl * 64 + nt * 16 + ml] = lastv[nt];
    }
}

// ---------- head: softmax(h2 @ Wd + bd) ----------
__global__ void head_kernel(const float* __restrict__ h2, const float* __restrict__ Wd,
                            const float* __restrict__ bd, float* __restrict__ out)
{
    int tid = threadIdx.x;         // 128 threads: b = tid>>1, c = tid&1
    int b = tid >> 1, c = tid & 1;
    float s = bd[c];
    for (int jj = 0; jj < 256; ++jj) s = fmaf(h2[b * 256 + jj], Wd[jj * 2 + c], s);
    __shared__ float lg[128];
    lg[tid] = s;
    __syncthreads();
    float o0 = lg[b * 2 + 0], o1 = lg[b * 2 + 1];
    float m = fmaxf(o0, o1);
    float z = __expf(o0 - m) + __expf(o1 - m);
    out[tid] = __expf(s - m) * __builtin_amdgcn_rcpf(z);
}

// ---------- launch ----------
extern "C" void kernel_launch(void* const* d_in, const int* in_sizes, int n_in,
                              void* d_out, int out_size, void* d_ws, size_t ws_size,
                              hipStream_t stream) {
    const int*   tokens = (const int*)d_in[0];
    const float* emb    = (const float*)d_in[1];
    const float* W1     = (const float*)d_in[2];
    const float* U1     = (const float*)d_in[3];
    const float* b1     = (const float*)d_in[4];
    const float* W2     = (const float*)d_in[5];
    const float* U2     = (const float*)d_in[6];
    const float* b2     = (const float*)d_in[7];
    const float* Wd     = (const float*)d_in[8];
    const float* bd     = (const float*)d_in[9];
    float* out = (float*)d_out;

    char* ws = (char*)d_ws;
    float*          xw  = (float*)ws;                                  // 32 MB (xw1 then xw2)
    unsigned short* h1  = (unsigned short*)(ws + (33554432));          // 16 MB bf16
    char*           p   = ws + 33554432 + 16777216;
    unsigned short* W1t = (unsigned short*)p;            p += 512 * 256 * 2;
    unsigned short* W2t = (unsigned short*)p;            p += 256 * 256 * 2;
    unsigned short* U1t = (unsigned short*)p;            p += 256 * 256 * 2;
    unsigned short* U2t = (unsigned short*)p;            p += 256 * 256 * 2;
    float*          h2  = (float*)p;

    const int M = 64 * 512;   // 32768

    // K0: weight/recurrence transposes to bf16 [N][K]
    transpose4<<<dim3(512, 4), 256, 0, stream>>>(W1, W2, U1, U2, W1t, W2t, U1t, U2t);

    // K1: xw1 = emb[tokens] @ W1 + b1   (gather fused)
    gemm_mfma<true><<<dim3(256 / 64, M / 64), 256, 0, stream>>>(
        emb, tokens, W1t, b1, xw, M, 256, 512);

    // K2: layer-1 scan -> h1 (bf16 sequence), 4 rows per WG
    rnn_scan_mfma<true><<<16, 256, 0, stream>>>(xw, U1t, h1, nullptr);

    // K3: xw2 = h1 @ W2 + b2
    gemm_mfma<false><<<dim3(256 / 64, M / 64), 256, 0, stream>>>(
        h1, nullptr, W2t, b2, xw, M, 256, 256);

    // K4: layer-2 scan -> h2 (last state, f32), 4 rows per WG
    rnn_scan_mfma<false><<<16, 256, 0, stream>>>(xw, U2t, nullptr, h2);

    // K5: softmax(h2 @ Wd + bd)
    head_kernel<<<1, 128, 0, stream>>>(h2, Wd, bd, out);
}

// Round 7
// 684.553 us; speedup vs baseline: 1.3509x; 1.0787x over previous
//
#include <hip/hip_runtime.h>

// ---------- types ----------
typedef __attribute__((ext_vector_type(8))) short bf16x8;
typedef __attribute__((ext_vector_type(4))) float f32x4;

static __device__ __forceinline__ unsigned short f2bf(float x) {
    unsigned int u = __float_as_uint(x);
    u += 0x7fffu + ((u >> 16) & 1u);   // RTNE, finite inputs
    return (unsigned short)(u >> 16);
}

// Workgroup barrier WITHOUT vmcnt drain: LDS ordering only.
// Safe when no global-memory producer/consumer relationship crosses the barrier.
static __device__ __forceinline__ void barrier_lds_only() {
    __asm__ volatile("s_waitcnt lgkmcnt(0)\n\ts_barrier" ::: "memory");
}

// ---------- K0: four fp32->bf16 transposes in one launch ----------
__global__ void transpose4(const float* __restrict__ s0, const float* __restrict__ s1,
                           const float* __restrict__ s2, const float* __restrict__ s3,
                           unsigned short* __restrict__ d0, unsigned short* __restrict__ d1,
                           unsigned short* __restrict__ d2, unsigned short* __restrict__ d3) {
    int which = blockIdx.y;
    const float* src = which == 0 ? s0 : which == 1 ? s1 : which == 2 ? s2 : s3;
    unsigned short* dst = which == 0 ? d0 : which == 1 ? d1 : which == 2 ? d2 : d3;
    int K = (which == 0) ? 512 : 256;
    int idx = blockIdx.x * 256 + threadIdx.x;
    if (idx >= K * 256) return;
    int k = idx >> 8;          // N = 256
    int n = idx & 255;
    dst[n * K + k] = f2bf(src[idx]);
}

// ---------- GEMM: bf16 MFMA, C = A[M,K] @ Bt[N,K]^T + bias ----------
// TOUT: store output TRANSPOSED as CT[b][n][t] (b = m>>9, t = m&511), so the
// scan can read 4 consecutive timesteps per thread as one float4.
template<bool GATHER>
__global__ __launch_bounds__(256, 4) void gemm_mfma(
    const void* __restrict__ Aptr, const int* __restrict__ tokens,
    const unsigned short* __restrict__ Bt, const float* __restrict__ bias,
    float* __restrict__ C, int M, int N, int K)
{
    const int bn0 = blockIdx.x * 64;
    const int m0  = blockIdx.y * 64;
    const int tid = threadIdx.x;

    __shared__ unsigned short As[64 * 40];
    __shared__ unsigned short Bs[64 * 40];
    __shared__ int tok[64];

    if (GATHER) {
        if (tid < 64) tok[tid] = tokens[m0 + tid];
        __syncthreads();
    }

    const int r  = tid >> 2;
    const int c0 = (tid & 3) * 8;
    const int w  = tid >> 6;
    const int L  = tid & 63;
    const int ml = L & 15;
    const int q  = L >> 4;
    const int kq = q * 8;

    f32x4 acc[4] = {};

    for (int k0 = 0; k0 < K; k0 += 32) {
        unsigned short tmp[8];
        if (GATHER) {
            const float* src = (const float*)Aptr + (size_t)tok[r] * K + k0 + c0;
            float4 f0 = *(const float4*)(src);
            float4 f1 = *(const float4*)(src + 4);
            tmp[0]=f2bf(f0.x); tmp[1]=f2bf(f0.y); tmp[2]=f2bf(f0.z); tmp[3]=f2bf(f0.w);
            tmp[4]=f2bf(f1.x); tmp[5]=f2bf(f1.y); tmp[6]=f2bf(f1.z); tmp[7]=f2bf(f1.w);
        } else {
            const unsigned short* src = (const unsigned short*)Aptr + (size_t)(m0 + r) * K + k0 + c0;
            *(uint4*)tmp = *(const uint4*)src;
        }
        *(uint4*)&As[r * 40 + c0] = *(const uint4*)tmp;
        *(uint4*)&Bs[r * 40 + c0] = *(const uint4*)(Bt + (size_t)(bn0 + r) * K + k0 + c0);
        __syncthreads();

        bf16x8 av = *(const bf16x8*)&As[(16 * w + ml) * 40 + kq];
#pragma unroll
        for (int ns = 0; ns < 4; ++ns) {
            bf16x8 bv = *(const bf16x8*)&Bs[(ns * 16 + ml) * 40 + kq];
            acc[ns] = __builtin_amdgcn_mfma_f32_16x16x32_bf16(av, bv, acc[ns], 0, 0, 0);
        }
        __syncthreads();
    }

    // Transposed epilogue: CT[b][gn][t], t = (m&511). acc reg rr <-> row q*4+rr,
    // rows are consecutive t -> one float4 store per n-tile.
    const int bb    = m0 >> 9;
    const int tbase = (m0 & 511) + 16 * w + q * 4;
#pragma unroll
    for (int ns = 0; ns < 4; ++ns) {
        int gn = bn0 + ns * 16 + ml;
        float bv = bias[gn];
        float4 v = { acc[ns][0] + bv, acc[ns][1] + bv, acc[ns][2] + bv, acc[ns][3] + bv };
        *(float4*)&C[(size_t)bb * 131072 + (size_t)gn * 512 + tbase] = v;
    }
}

// ---------- MFMA scan: h_t = tanh(xwT_t + h_{t-1} @ U), one WG (256 thr) per batch row ----------
// R4 structure (1 row/WG, double-buffered h, one lds-only barrier/step) with the
// xw stream CHUNKED: xwT is [b][col][t], one float4 = 4 timesteps, loaded 2 groups
// (8 steps) ahead -> vm wait amortized over 4 steps and never latency-exposed.
template<bool SEQ>
__global__ __launch_bounds__(256, 1) void rnn_scan_mfma(
    const float* __restrict__ xwT,          // [64][256][512] f32 (transposed)
    const unsigned short* __restrict__ Ut,  // [256][256] bf16, Ut[n][k] = U[k][n]
    unsigned short* __restrict__ out_seq,   // bf16 [64][512][256]  (SEQ)
    float* __restrict__ out_last)           // f32 [64][256]        (!SEQ)
{
    const int b   = blockIdx.x;
    const int tid = threadIdx.x;
    const int w   = tid >> 6;       // wave 0..3
    const int L   = tid & 63;
    const int col = w * 64 + L;     // this thread's output column (L = q*16+ml)
    const int q   = L >> 4;         // quad; thread's chain index nt == q
    const int ml  = L & 15;

    __shared__ unsigned short hsh[2][256];

    // B-frags: U columns for this wave's 4 n-tiles, all 8 k-tiles
    bf16x8 ufrag[4][8];
#pragma unroll
    for (int i = 0; i < 4; ++i) {
        const unsigned short* up = Ut + (size_t)((w * 4 + i) * 16 + ml) * 256 + q * 8;
#pragma unroll
        for (int kt = 0; kt < 8; ++kt)
            ufrag[i][kt] = *(const bf16x8*)(up + kt * 32);
    }

    hsh[0][tid] = 0;   // bf16 +0.0

    const float* xb = xwT + (size_t)b * 131072 + (size_t)col * 512;
    unsigned short* op = SEQ ? out_seq + (size_t)b * 512 * 256 + col : nullptr;

    // preload chunks 0 and 1 (t=0..7)
    float4 cch0 = *(const float4*)(xb);
    float4 cch1 = *(const float4*)(xb + 4);

    const f32x4 zf = {0.f, 0.f, 0.f, 0.f};  // loop-invariant zero C operand
    float lastv = 0.f;
    __syncthreads();

#define SCAN_STEP(CUR, XV)                                                           \
    {                                                                                \
        bf16x8 af[8];                                                                \
        _Pragma("unroll")                                                            \
        for (int kt = 0; kt < 8; ++kt)                                               \
            af[kt] = *(const bf16x8*)&hsh[CUR][kt * 32 + q * 8];                     \
        f32x4 accA[4], accB[4];                                                      \
        _Pragma("unroll")                                                            \
        for (int i = 0; i < 4; ++i)                                                  \
            accA[i] = __builtin_amdgcn_mfma_f32_16x16x32_bf16(af[0], ufrag[i][0], zf, 0, 0, 0); \
        _Pragma("unroll")                                                            \
        for (int i = 0; i < 4; ++i)                                                  \
            accB[i] = __builtin_amdgcn_mfma_f32_16x16x32_bf16(af[1], ufrag[i][1], zf, 0, 0, 0); \
        _Pragma("unroll")                                                            \
        for (int kt = 2; kt < 8; kt += 2) {                                          \
            _Pragma("unroll")                                                        \
            for (int i = 0; i < 4; ++i)                                              \
                accA[i] = __builtin_amdgcn_mfma_f32_16x16x32_bf16(af[kt], ufrag[i][kt], accA[i], 0, 0, 0);       \
            _Pragma("unroll")                                                        \
            for (int i = 0; i < 4; ++i)                                              \
                accB[i] = __builtin_amdgcn_mfma_f32_16x16x32_bf16(af[kt + 1], ufrag[i][kt + 1], accB[i], 0, 0, 0); \
        }                                                                            \
        float zA = (q == 0) ? accA[0][0] : (q == 1) ? accA[1][0] : (q == 2) ? accA[2][0] : accA[3][0]; \
        float zB = (q == 0) ? accB[0][0] : (q == 1) ? accB[1][0] : (q == 2) ? accB[2][0] : accB[3][0]; \
        float z  = zA + zB + (XV);                                                   \
        float e  = __expf(2.f * z);               /* tanh(z) = 1 - 2/(e^{2z}+1) */   \
        float hn = 1.f - 2.f * __builtin_amdgcn_rcpf(e + 1.f);                       \
        lastv = hn;                                                                  \
        unsigned short hb = f2bf(hn);                                                \
        hsh[(CUR) ^ 1][col] = hb;                                                    \
        if (SEQ) { *op = hb; op += 256; }                                            \
        barrier_lds_only();                       /* h_new visible; no vmcnt drain */\
    }

    // steady state: 63 iterations x 2 groups (groups 0..125); each group issues
    // its g+2 chunk load FIRST (stores are younger -> wait never includes them)
    for (int g = 0; g < 126; g += 2) {
        {
            float4 nx = *(const float4*)(xb + 4 * g + 8);
            SCAN_STEP(0, cch0.x)
            SCAN_STEP(1, cch0.y)
            SCAN_STEP(0, cch0.z)
            SCAN_STEP(1, cch0.w)
            cch0 = nx;
        }
        {
            float4 nx = *(const float4*)(xb + 4 * g + 12);
            SCAN_STEP(0, cch1.x)
            SCAN_STEP(1, cch1.y)
            SCAN_STEP(0, cch1.z)
            SCAN_STEP(1, cch1.w)
            cch1 = nx;
        }
    }
    // epilogue: groups 126, 127 (t = 504..511), no loads
    SCAN_STEP(0, cch0.x)
    SCAN_STEP(1, cch0.y)
    SCAN_STEP(0, cch0.z)
    SCAN_STEP(1, cch0.w)
    SCAN_STEP(0, cch1.x)
    SCAN_STEP(1, cch1.y)
    SCAN_STEP(0, cch1.z)
    SCAN_STEP(1, cch1.w)
#undef SCAN_STEP

    if (!SEQ) out_last[b * 256 + col] = lastv;
}

// ---------- head: softmax(h2 @ Wd + bd) ----------
__global__ void head_kernel(const float* __restrict__ h2, const float* __restrict__ Wd,
                            const float* __restrict__ bd, float* __restrict__ out)
{
    int tid = threadIdx.x;         // 128 threads: b = tid>>1, c = tid&1
    int b = tid >> 1, c = tid & 1;
    float s = bd[c];
    for (int jj = 0; jj < 256; ++jj) s = fmaf(h2[b * 256 + jj], Wd[jj * 2 + c], s);
    __shared__ float lg[128];
    lg[tid] = s;
    __syncthreads();
    float o0 = lg[b * 2 + 0], o1 = lg[b * 2 + 1];
    float m = fmaxf(o0, o1);
    float z = __expf(o0 - m) + __expf(o1 - m);
    out[tid] = __expf(s - m) * __builtin_amdgcn_rcpf(z);
}

// ---------- launch ----------
extern "C" void kernel_launch(void* const* d_in, const int* in_sizes, int n_in,
                              void* d_out, int out_size, void* d_ws, size_t ws_size,
                              hipStream_t stream) {
    const int*   tokens = (const int*)d_in[0];
    const float* emb    = (const float*)d_in[1];
    const float* W1     = (const float*)d_in[2];
    const float* U1     = (const float*)d_in[3];
    const float* b1     = (const float*)d_in[4];
    const float* W2     = (const float*)d_in[5];
    const float* U2     = (const float*)d_in[6];
    const float* b2     = (const float*)d_in[7];
    const float* Wd     = (const float*)d_in[8];
    const float* bd     = (const float*)d_in[9];
    float* out = (float*)d_out;

    char* ws = (char*)d_ws;
    float*          xwT = (float*)ws;                                  // 32 MB [b][col][t]
    unsigned short* h1  = (unsigned short*)(ws + (33554432));          // 16 MB bf16 [b][t][col]
    char*           p   = ws + 33554432 + 16777216;
    unsigned short* W1t = (unsigned short*)p;            p += 512 * 256 * 2;
    unsigned short* W2t = (unsigned short*)p;            p += 256 * 256 * 2;
    unsigned short* U1t = (unsigned short*)p;            p += 256 * 256 * 2;
    unsigned short* U2t = (unsigned short*)p;            p += 256 * 256 * 2;
    float*          h2  = (float*)p;

    const int M = 64 * 512;   // 32768

    // K0: weight/recurrence transposes to bf16 [N][K]
    transpose4<<<dim3(512, 4), 256, 0, stream>>>(W1, W2, U1, U2, W1t, W2t, U1t, U2t);

    // K1: xw1 = emb[tokens] @ W1 + b1   (gather fused, transposed store)
    gemm_mfma<true><<<dim3(256 / 64, M / 64), 256, 0, stream>>>(
        emb, tokens, W1t, b1, xwT, M, 256, 512);

    // K2: layer-1 scan -> h1 (bf16 sequence, [b][t][col])
    rnn_scan_mfma<true><<<64, 256, 0, stream>>>(xwT, U1t, h1, nullptr);

    // K3: xw2 = h1 @ W2 + b2   (transposed store)
    gemm_mfma<false><<<dim3(256 / 64, M / 64), 256, 0, stream>>>(
        h1, nullptr, W2t, b2, xwT, M, 256, 256);

    // K4: layer-2 scan -> h2 (last state, f32)
    rnn_scan_mfma<false><<<64, 256, 0, stream>>>(xwT, U2t, nullptr, h2);

    // K5: softmax(h2 @ Wd + bd)
    head_kernel<<<1, 128, 0, stream>>>(h2, Wd, bd, out);
}